// Round 8
// baseline (919.539 us; speedup 1.0000x reference)
//
#include <hip/hip_runtime.h>
#include <hip/hip_bf16.h>
#include <stdint.h>

#define NE 800000
#define NN 50000

// ---- weight region (float offsets). O_W2 / O_WN2 hold TRANSPOSED weights.
#define O_W1   0          // We1  [129*64] row-major
#define O_B1   8256
#define O_W2   8320       // We2^T [64*64]
#define O_B2   12416
#define O_WC1  12480      // Wc1  [64*64] row-major
#define O_BC1  16576
#define O_WC2  16640
#define O_BC2  16704
#define O_WN1  16768      // Wn1  [128*64] row-major
#define O_BN1  24960
#define O_WN2  25024      // Wn2^T [64*64]
#define O_BN2  29120
#define O_FLAG 29184      // int: 1 = tensors bf16, 0 = f32

// ---- per-node layer-1 precompute, stored bf16-packed:
// node n: uints [0:32) = yr (h[n]@We1[0:64]), [32:64) = yc (h[n]@We1[64:128])
#define O_Y    29248                    // uint [NN*64] (4B words)
#define Y_END  (O_Y + NN*64)            // 3,229,248

// ---- CSR layout ----
#define N_OFF   Y_END                   // int off[NN+1] (padded)
#define N_CUR   (N_OFF + 50008)
#define N_ELIST (N_CUR + NN)
#define N_AGGH  (N_ELIST + NE)          // float [NN*64]
#define N_SUMT  (N_AGGH + NN*64)        // float [NN*3]
#define N_EF16  (N_SUMT + NN*3)         // bf16 ef: NE*32 uints (word off %4==0 -> 16B aligned)
#define N_TR    (N_EF16 + NE*32)        // float [NE*3]
#define N_TOTAL (N_TR + NE*3)           // ~35.5M words ~ 142 MB

// ---- atomic fallback layout ----
#define F_AGGH  Y_END
#define F_SUMT  (F_AGGH + NN*64)
#define F_CNT   (F_SUMT + NN*3)
#define F_TOTAL (F_CNT + NN)

#define OUT_COORD (NN*64)
#define OUT_V     (NN*64 + NN*3)

typedef float v2f __attribute__((ext_vector_type(2)));

static __device__ __forceinline__ v2f fma2(v2f a, v2f b, v2f c) {
#if __has_builtin(__builtin_elementwise_fma)
    return __builtin_elementwise_fma(a, b, c);   // -> v_pk_fma_f32
#else
    v2f r; r.x = fmaf(a.x, b.x, c.x); r.y = fmaf(a.y, b.y, c.y); return r;
#endif
}
static __device__ __forceinline__ v2f splat2(float s) { v2f r; r.x = s; r.y = s; return r; }
static __device__ __forceinline__ v2f relu2(v2f a) { a.x = fmaxf(a.x, 0.0f); a.y = fmaxf(a.y, 0.0f); return a; }
static __device__ __forceinline__ v2f bf2x(uint32_t u) {
    v2f r; r.x = __uint_as_float(u << 16); r.y = __uint_as_float(u & 0xffff0000u); return r;
}

static __device__ __forceinline__ float bf2f(const __hip_bfloat16 x) { return __bfloat162float(x); }

template<bool B16>
static __device__ __forceinline__ float ldf(const void* p, size_t i) {
    if (B16) return __bfloat162float(((const __hip_bfloat16*)p)[i]);
    else     return ((const float*)p)[i];
}
template<bool B16>
static __device__ __forceinline__ void stf(void* p, size_t i, float v) {
    if (B16) ((__hip_bfloat16*)p)[i] = __float2bfloat16(v);
    else     ((float*)p)[i] = v;
}
template<bool B16>
static __device__ __forceinline__ float4 ld4(const void* p, size_t i4) {
    if (B16) {
        uint2 u = ((const uint2*)p)[i4];
        return make_float4(__uint_as_float(u.x << 16), __uint_as_float(u.x & 0xffff0000u),
                           __uint_as_float(u.y << 16), __uint_as_float(u.y & 0xffff0000u));
    } else {
        return ((const float4*)p)[i4];
    }
}
template<bool B16>
static __device__ __forceinline__ void st4(void* p, size_t i4, float4 v) {
    if (B16) {
        stf<true>(p, 4*i4 + 0, v.x); stf<true>(p, 4*i4 + 1, v.y);
        stf<true>(p, 4*i4 + 2, v.z); stf<true>(p, 4*i4 + 3, v.w);
    } else {
        ((float4*)p)[i4] = v;
    }
}
static __device__ __forceinline__ unsigned short f2bf_bits(float x) {
    __hip_bfloat16 b = __float2bfloat16(x);
    return *reinterpret_cast<unsigned short*>(&b);
}
static __device__ __forceinline__ uint32_t pack_bf2(float lo, float hi) {
    return (uint32_t)f2bf_bits(lo) | ((uint32_t)f2bf_bits(hi) << 16);
}

// ---- dtype sniff (see R2): P(wrong) ~ 0.48^128 ----
__global__ void sniff_kernel(const uint32_t* __restrict__ w, float* __restrict__ ws) {
    int bad = 0;
    for (int i = 0; i < 128; ++i) {
        uint32_t d = w[i];
        float a = __uint_as_float(d << 16);
        float b = __uint_as_float(d & 0xffff0000u);
        if (!(fabsf(a) <= 0.1f)) bad++;
        if (!(fabsf(b) <= 0.1f)) bad++;
    }
    ((int*)ws)[O_FLAG] = (bad == 0) ? 1 : 0;
}

// ---- weights -> fp32 in ws; W2/Wn2 transposed ----
__global__ void prep_kernel(
    const void* We1, const void* be1, const void* We2, const void* be2,
    const void* Wn1, const void* bn1, const void* Wn2, const void* bn2,
    const void* Wc1, const void* bc1, const void* Wc2, const void* bc2,
    float* __restrict__ wf)
{
    const int isb = ((const int*)wf)[O_FLAG];
    int tid = blockIdx.x * blockDim.x + threadIdx.x;
    int stride = gridDim.x * blockDim.x;
#define LD(src, i) (isb ? bf2f(((const __hip_bfloat16*)(src))[i]) : ((const float*)(src))[i])
#define CP(dst, src, n)  for (int i = tid; i < (n); i += stride) wf[(dst) + i] = LD(src, i);
#define CPT(dst, src)    for (int i = tid; i < 4096; i += stride) \
        wf[(dst) + (i & 63) * 64 + (i >> 6)] = LD(src, i);
    CP(O_W1,  We1, 129*64)  CP(O_B1,  be1, 64)
    CPT(O_W2,  We2)         CP(O_B2,  be2, 64)
    CP(O_WC1, Wc1, 64*64)   CP(O_BC1, bc1, 64)
    CP(O_WC2, Wc2, 64)      CP(O_BC2, bc2, 1)
    CP(O_WN1, Wn1, 128*64)  CP(O_BN1, bn1, 64)
    CPT(O_WN2, Wn2)         CP(O_BN2, bn2, 64)
#undef CP
#undef CPT
#undef LD
}

// ---- per-node layer-1 partials, packed math, bf16-packed output ----
template<bool B16>
static __device__ __forceinline__ void pre_edge_core(
    const void* __restrict__ h, float* __restrict__ ws, int n)
{
    v2f yr[32], yc[32];
    #pragma unroll
    for (int q = 0; q < 32; ++q) { yr[q] = splat2(0.0f); yc[q] = splat2(0.0f); }
    #pragma unroll 4
    for (int q = 0; q < 16; ++q) {
        float4 a = ld4<B16>(h, (size_t)n * 16 + q);
        #pragma unroll
        for (int u = 0; u < 4; ++u) {
            int k = q * 4 + u;
            float av = (u == 0) ? a.x : (u == 1) ? a.y : (u == 2) ? a.z : a.w;
            v2f av2 = splat2(av);
            const v2f* w  = (const v2f*)(ws + O_W1 + k * 64);
            const v2f* w2 = (const v2f*)(ws + O_W1 + (64 + k) * 64);
            #pragma unroll
            for (int j = 0; j < 32; ++j) yr[j] = fma2(av2, w[j], yr[j]);
            #pragma unroll
            for (int j = 0; j < 32; ++j) yc[j] = fma2(av2, w2[j], yc[j]);
        }
    }
    uint4* yv = (uint4*)((uint32_t*)ws + O_Y + (size_t)n * 64);
    #pragma unroll
    for (int q = 0; q < 8; ++q)
        yv[q] = make_uint4(pack_bf2(yr[4*q+0].x, yr[4*q+0].y), pack_bf2(yr[4*q+1].x, yr[4*q+1].y),
                           pack_bf2(yr[4*q+2].x, yr[4*q+2].y), pack_bf2(yr[4*q+3].x, yr[4*q+3].y));
    #pragma unroll
    for (int q = 0; q < 8; ++q)
        yv[8+q] = make_uint4(pack_bf2(yc[4*q+0].x, yc[4*q+0].y), pack_bf2(yc[4*q+1].x, yc[4*q+1].y),
                             pack_bf2(yc[4*q+2].x, yc[4*q+2].y), pack_bf2(yc[4*q+3].x, yc[4*q+3].y));
}

__global__ __launch_bounds__(256, 2) void pre_edge_kernel(
    const void* __restrict__ h, float* __restrict__ ws)
{
    int n = blockIdx.x * 256 + threadIdx.x;
    if (n >= NN) return;
    if (((const int*)ws)[O_FLAG]) pre_edge_core<true>(h, ws, n);
    else                          pre_edge_core<false>(h, ws, n);
}

// ---- edge core: layer1 from bf16 Y, packed-math phases B/C ----
template<bool B16>
static __device__ __forceinline__ void edge_mlp(
    const void* __restrict__ coord, const float* __restrict__ wf,
    int row, int col,
    float4 efbuf[16], float& gate, float& cdx, float& cdy, float& cdz)
{
    cdx = ldf<B16>(coord, 3*row + 0) - ldf<B16>(coord, 3*col + 0);
    cdy = ldf<B16>(coord, 3*row + 1) - ldf<B16>(coord, 3*col + 1);
    cdz = ldf<B16>(coord, 3*row + 2) - ldf<B16>(coord, 3*col + 2);
    float radial = cdx*cdx + cdy*cdy + cdz*cdz;

    const uint4* yru = (const uint4*)((const uint32_t*)wf + O_Y + (size_t)row * 64);
    const uint4* ycu = (const uint4*)((const uint32_t*)wf + O_Y + (size_t)col * 64 + 32);
    uint4 yr[8], yc[8];
    #pragma unroll
    for (int q = 0; q < 8; ++q) yr[q] = yru[q];
    #pragma unroll
    for (int q = 0; q < 8; ++q) yc[q] = ycu[q];

    const v2f* b12 = (const v2f*)(wf + O_B1);
    const v2f* wr2 = (const v2f*)(wf + O_W1 + 128 * 64);
    v2f radial2 = splat2(radial);

    v2f acc[32];
    #pragma unroll
    for (int q = 0; q < 8; ++q) {
        #pragma unroll
        for (int u = 0; u < 4; ++u) {
            int i = q * 4 + u;
            uint32_t ur = (u == 0) ? yr[q].x : (u == 1) ? yr[q].y : (u == 2) ? yr[q].z : yr[q].w;
            uint32_t uc = (u == 0) ? yc[q].x : (u == 1) ? yc[q].y : (u == 2) ? yc[q].z : yc[q].w;
            acc[i] = relu2(fma2(radial2, wr2[i], b12[i] + bf2x(ur) + bf2x(uc)));
        }
    }

    // phase B: ef[j] = relu(acc . We2^T_j + b2_j)
    #pragma unroll
    for (int j0 = 0; j0 < 16; ++j0) {
        float c[4];
        #pragma unroll
        for (int u = 0; u < 4; ++u) {
            int j = j0 * 4 + u;
            const v2f* w2t = (const v2f*)(wf + O_W2 + j * 64);
            v2f t2 = splat2(0.0f);
            #pragma unroll
            for (int k = 0; k < 32; ++k) t2 = fma2(acc[k], w2t[k], t2);
            c[u] = fmaxf(t2.x + t2.y + wf[O_B2 + j], 0.0f);
        }
        efbuf[j0] = make_float4(c[0], c[1], c[2], c[3]);
    }

    // phase C: hid = bc1 + ef . Wc1
    v2f hid[32];
    const v2f* bc12 = (const v2f*)(wf + O_BC1);
    #pragma unroll
    for (int q = 0; q < 32; ++q) hid[q] = bc12[q];
    #pragma unroll
    for (int j0 = 0; j0 < 16; ++j0) {
        float4 ef4 = efbuf[j0];
        #pragma unroll
        for (int u = 0; u < 4; ++u) {
            int j = j0 * 4 + u;
            float ef = (u == 0) ? ef4.x : (u == 1) ? ef4.y : (u == 2) ? ef4.z : ef4.w;
            v2f ef2 = splat2(ef);
            const v2f* wc1 = (const v2f*)(wf + O_WC1 + j * 64);
            #pragma unroll
            for (int q = 0; q < 32; ++q) hid[q] = fma2(ef2, wc1[q], hid[q]);
        }
    }

    const v2f* wc22 = (const v2f*)(wf + O_WC2);
    v2f g2 = splat2(0.0f);
    #pragma unroll
    for (int q = 0; q < 32; ++q) g2 = fma2(relu2(hid[q]), wc22[q], g2);
    gate = g2.x + g2.y + wf[O_BC2];
}

// ============ CSR path ============
template<bool B16>
static __device__ __forceinline__ void edge_store_core(
    const void* __restrict__ coord, const int* __restrict__ ei,
    float* __restrict__ ws, int e)
{
    int row = ei[e];
    int col = ei[NE + e];
    float gate, cdx, cdy, cdz;
    float4 efbuf[16];
    edge_mlp<B16>(coord, ws, row, col, efbuf, gate, cdx, cdy, cdz);

    // batched stores (R5 lesson)
    uint4* efv = (uint4*)(ws + N_EF16) + (size_t)e * 8;
    #pragma unroll
    for (int q = 0; q < 8; ++q) {
        float4 a = efbuf[2*q], b = efbuf[2*q + 1];
        efv[q] = make_uint4(pack_bf2(a.x, a.y), pack_bf2(a.z, a.w),
                            pack_bf2(b.x, b.y), pack_bf2(b.z, b.w));
    }
    ws[N_TR + 3*e + 0] = fminf(fmaxf(cdx * gate, -100.0f), 100.0f);
    ws[N_TR + 3*e + 1] = fminf(fmaxf(cdy * gate, -100.0f), 100.0f);
    ws[N_TR + 3*e + 2] = fminf(fmaxf(cdz * gate, -100.0f), 100.0f);

    atomicAdd((int*)ws + N_CUR + row, 1);
}

__global__ __launch_bounds__(256, 2) void edge_store_kernel(
    const void* __restrict__ coord, const int* __restrict__ ei,
    float* __restrict__ ws)
{
    int e = blockIdx.x * 256 + threadIdx.x;
    if (e >= NE) return;
    if (((const int*)ws)[O_FLAG]) edge_store_core<true>(coord, ei, ws, e);
    else                          edge_store_core<false>(coord, ei, ws, e);
}

// shfl-based single-block exclusive scan
__global__ __launch_bounds__(1024) void scan_kernel(float* __restrict__ ws) {
    int* cnt = (int*)ws + N_CUR;
    int* off = (int*)ws + N_OFF;
    __shared__ int wsum[16];
    __shared__ int carry_s;
    int tid = threadIdx.x, lane = tid & 63, wid = tid >> 6;
    if (tid == 0) carry_s = 0;
    __syncthreads();
    for (int base = 0; base < NN; base += 1024) {
        int i = base + tid;
        int orig = (i < NN) ? cnt[i] : 0;
        int v = orig;
        #pragma unroll
        for (int s = 1; s < 64; s <<= 1) { int t = __shfl_up(v, s, 64); if (lane >= s) v += t; }
        if (lane == 63) wsum[wid] = v;
        __syncthreads();
        if (wid == 0) {
            int w = (lane < 16) ? wsum[lane] : 0;
            #pragma unroll
            for (int s = 1; s < 16; s <<= 1) { int t = __shfl_up(w, s, 64); if (lane >= s) w += t; }
            if (lane < 16) wsum[lane] = w;
        }
        __syncthreads();
        int waveback = (wid > 0) ? wsum[wid - 1] : 0;
        int excl = carry_s + waveback + v - orig;
        if (i < NN) { off[i] = excl; cnt[i] = excl; }
        __syncthreads();
        if (tid == 0) carry_s += wsum[15];
        __syncthreads();
    }
    if (threadIdx.x == 0) off[NN] = carry_s;
}

__global__ __launch_bounds__(256) void scatter_kernel(
    const int* __restrict__ ei, float* __restrict__ ws)
{
    int e = blockIdx.x * 256 + threadIdx.x;
    if (e >= NE) return;
    int row = ei[e];
    int pos = atomicAdd((int*)ws + N_CUR + row, 1);
    ((int*)ws)[N_ELIST + pos] = e;
}

// one wave per node, 4-deep pipelined gather over the edge list
__global__ __launch_bounds__(256) void agg_kernel(float* __restrict__ ws) {
    int node = (blockIdx.x * 256 + threadIdx.x) >> 6;
    int lane = threadIdx.x & 63;
    if (node >= NN) return;
    const int* off = (const int*)ws + N_OFF;
    const int* elist = (const int*)ws + N_ELIST;
    const unsigned short* ef16 = (const unsigned short*)(ws + N_EF16);
    const float* tr = ws + N_TR;
    int s = off[node], t = off[node + 1];
    float sum = 0.0f, ts = 0.0f;
    int i = s;
    for (; i + 4 <= t; i += 4) {
        int e0 = elist[i], e1 = elist[i+1], e2 = elist[i+2], e3 = elist[i+3];
        unsigned short u0 = ef16[(size_t)e0 * 64 + lane];
        unsigned short u1 = ef16[(size_t)e1 * 64 + lane];
        unsigned short u2 = ef16[(size_t)e2 * 64 + lane];
        unsigned short u3 = ef16[(size_t)e3 * 64 + lane];
        float t0 = 0.0f, t1 = 0.0f, t2v = 0.0f, t3 = 0.0f;
        if (lane < 3) {
            t0 = tr[3*e0 + lane]; t1 = tr[3*e1 + lane];
            t2v = tr[3*e2 + lane]; t3 = tr[3*e3 + lane];
        }
        sum += __uint_as_float((uint32_t)u0 << 16) + __uint_as_float((uint32_t)u1 << 16)
             + __uint_as_float((uint32_t)u2 << 16) + __uint_as_float((uint32_t)u3 << 16);
        ts += (t0 + t1) + (t2v + t3);
    }
    for (; i < t; ++i) {
        int ed = elist[i];
        unsigned short u = ef16[(size_t)ed * 64 + lane];
        sum += __uint_as_float((uint32_t)u << 16);
        if (lane < 3) ts += tr[3*ed + lane];
    }
    ws[N_AGGH + (size_t)node * 64 + lane] = sum;
    if (lane < 3) ws[N_SUMT + 3*node + lane] = ts;
}

// ---- node core, packed math, batched stores ----
template<bool B16>
static __device__ __forceinline__ void node_core(
    const void* __restrict__ h, const void* __restrict__ coord,
    const void* __restrict__ vel, const float* __restrict__ ws,
    const float* __restrict__ agg, const float* __restrict__ sumt, float cntf,
    void* __restrict__ out, int n)
{
    float inv = (cntf > 0.0f) ? (1.0f / fmaxf(cntf, 1.0f)) : 0.0f;
    #pragma unroll
    for (int i = 0; i < 3; ++i) {
        float aggc = sumt[3*n + i] * inv;
        float v = ldf<B16>(vel, 3*n + i) + aggc * 0.125f;
        float cn = ldf<B16>(coord, 3*n + i) + v * 0.125f;
        stf<B16>(out, OUT_COORD + 3*n + i, cn);
        stf<B16>(out, OUT_V + 3*n + i, v);
    }

    v2f acc[32];
    const v2f* bn12 = (const v2f*)(ws + O_BN1);
    #pragma unroll
    for (int q = 0; q < 32; ++q) acc[q] = bn12[q];

    #pragma unroll 4
    for (int q = 0; q < 16; ++q) {
        float4 a = ld4<B16>(h, (size_t)n * 16 + q);
        #pragma unroll
        for (int u = 0; u < 4; ++u) {
            int k = q * 4 + u;
            float av = (u == 0) ? a.x : (u == 1) ? a.y : (u == 2) ? a.z : a.w;
            v2f av2 = splat2(av);
            const v2f* w = (const v2f*)(ws + O_WN1 + k * 64);
            #pragma unroll
            for (int j = 0; j < 32; ++j) acc[j] = fma2(av2, w[j], acc[j]);
        }
    }
    const float4* agv = (const float4*)(agg + (size_t)n * 64);
    #pragma unroll 4
    for (int q = 0; q < 16; ++q) {
        float4 a = agv[q];
        #pragma unroll
        for (int u = 0; u < 4; ++u) {
            int k = 64 + q * 4 + u;
            float av = (u == 0) ? a.x : (u == 1) ? a.y : (u == 2) ? a.z : a.w;
            v2f av2 = splat2(av);
            const v2f* w = (const v2f*)(ws + O_WN1 + k * 64);
            #pragma unroll
            for (int j = 0; j < 32; ++j) acc[j] = fma2(av2, w[j], acc[j]);
        }
    }
    #pragma unroll
    for (int q = 0; q < 32; ++q) acc[q] = relu2(acc[q]);

    float4 ob[16];
    #pragma unroll
    for (int j0 = 0; j0 < 16; ++j0) {
        float4 hres = ld4<B16>(h, (size_t)n * 16 + j0);
        float c[4];
        #pragma unroll
        for (int u = 0; u < 4; ++u) {
            int j = j0 * 4 + u;
            const v2f* w = (const v2f*)(ws + O_WN2 + j * 64);
            v2f t2 = splat2(0.0f);
            #pragma unroll
            for (int k = 0; k < 32; ++k) t2 = fma2(acc[k], w[k], t2);
            c[u] = t2.x + t2.y + ws[O_BN2 + j];
        }
        ob[j0] = make_float4(hres.x + c[0], hres.y + c[1], hres.z + c[2], hres.w + c[3]);
    }
    #pragma unroll
    for (int j0 = 0; j0 < 16; ++j0) st4<B16>(out, (size_t)n * 16 + j0, ob[j0]);
}

__global__ __launch_bounds__(256, 2) void node_kernel_csr(
    const void* __restrict__ h, const void* __restrict__ coord,
    const void* __restrict__ vel, const float* __restrict__ ws,
    void* __restrict__ out)
{
    int n = blockIdx.x * 256 + threadIdx.x;
    if (n >= NN) return;
    const int* off = (const int*)ws + N_OFF;
    float cntf = (float)(off[n + 1] - off[n]);
    if (((const int*)ws)[O_FLAG])
        node_core<true>(h, coord, vel, ws, ws + N_AGGH, ws + N_SUMT, cntf, out, n);
    else
        node_core<false>(h, coord, vel, ws, ws + N_AGGH, ws + N_SUMT, cntf, out, n);
}

// ============ atomic fallback (small ws) ============
template<bool B16>
static __device__ __forceinline__ void edge_atomic_core(
    const void* __restrict__ coord, const int* __restrict__ ei,
    float* __restrict__ ws, int e)
{
    int row = ei[e];
    int col = ei[NE + e];
    float gate, cdx, cdy, cdz;
    float4 efbuf[16];
    edge_mlp<B16>(coord, ws, row, col, efbuf, gate, cdx, cdy, cdz);

    float* ah = ws + F_AGGH + (size_t)row * 64;
    #pragma unroll
    for (int q = 0; q < 16; ++q) {
        unsafeAtomicAdd(&ah[4*q + 0], efbuf[q].x);
        unsafeAtomicAdd(&ah[4*q + 1], efbuf[q].y);
        unsafeAtomicAdd(&ah[4*q + 2], efbuf[q].z);
        unsafeAtomicAdd(&ah[4*q + 3], efbuf[q].w);
    }
    unsafeAtomicAdd(&ws[F_SUMT + 3*row + 0], fminf(fmaxf(cdx * gate, -100.0f), 100.0f));
    unsafeAtomicAdd(&ws[F_SUMT + 3*row + 1], fminf(fmaxf(cdy * gate, -100.0f), 100.0f));
    unsafeAtomicAdd(&ws[F_SUMT + 3*row + 2], fminf(fmaxf(cdz * gate, -100.0f), 100.0f));
    unsafeAtomicAdd(&ws[F_CNT + row], 1.0f);
}

__global__ __launch_bounds__(256, 2) void edge_atomic_kernel(
    const void* __restrict__ coord, const int* __restrict__ ei,
    float* __restrict__ ws)
{
    int e = blockIdx.x * 256 + threadIdx.x;
    if (e >= NE) return;
    if (((const int*)ws)[O_FLAG]) edge_atomic_core<true>(coord, ei, ws, e);
    else                          edge_atomic_core<false>(coord, ei, ws, e);
}

__global__ __launch_bounds__(256, 2) void node_kernel_atomic(
    const void* __restrict__ h, const void* __restrict__ coord,
    const void* __restrict__ vel, const float* __restrict__ ws,
    void* __restrict__ out)
{
    int n = blockIdx.x * 256 + threadIdx.x;
    if (n >= NN) return;
    float cntf = ws[F_CNT + n];
    if (((const int*)ws)[O_FLAG])
        node_core<true>(h, coord, vel, ws, ws + F_AGGH, ws + F_SUMT, cntf, out, n);
    else
        node_core<false>(h, coord, vel, ws, ws + F_AGGH, ws + F_SUMT, cntf, out, n);
}

extern "C" void kernel_launch(void* const* d_in, const int* in_sizes, int n_in,
                              void* d_out, int out_size, void* d_ws, size_t ws_size,
                              hipStream_t stream) {
    const void* h     = d_in[0];
    const void* coord = d_in[1];
    const void* vel   = d_in[2];
    const int* eidx = (const int*)d_in[4];
    float* ws = (float*)d_ws;

    sniff_kernel<<<1, 1, 0, stream>>>((const uint32_t*)d_in[5], ws);
    prep_kernel<<<64, 256, 0, stream>>>(d_in[5], d_in[6], d_in[7], d_in[8],
                                        d_in[9], d_in[10], d_in[11], d_in[12],
                                        d_in[13], d_in[14], d_in[15], d_in[16], ws);
    pre_edge_kernel<<<(NN + 255) / 256, 256, 0, stream>>>(h, ws);

    const bool big = ws_size >= (size_t)N_TOTAL * sizeof(float);
    if (big) {
        hipMemsetAsync((char*)d_ws + (size_t)N_CUR * 4, 0, (size_t)NN * 4, stream);
        edge_store_kernel<<<(NE + 255) / 256, 256, 0, stream>>>(coord, eidx, ws);
        scan_kernel<<<1, 1024, 0, stream>>>(ws);
        scatter_kernel<<<(NE + 255) / 256, 256, 0, stream>>>(eidx, ws);
        agg_kernel<<<(NN * 64 + 255) / 256, 256, 0, stream>>>(ws);
        node_kernel_csr<<<(NN + 255) / 256, 256, 0, stream>>>(h, coord, vel, ws, d_out);
    } else {
        hipMemsetAsync((char*)d_ws + (size_t)F_AGGH * 4, 0,
                       (size_t)(F_TOTAL - F_AGGH) * 4, stream);
        edge_atomic_kernel<<<(NE + 255) / 256, 256, 0, stream>>>(coord, eidx, ws);
        node_kernel_atomic<<<(NN + 255) / 256, 256, 0, stream>>>(h, coord, vel, ws, d_out);
    }
}

// Round 9
// 789.564 us; speedup vs baseline: 1.1646x; 1.1646x over previous
//
#include <hip/hip_runtime.h>
#include <hip/hip_bf16.h>
#include <stdint.h>

#define NE 800000
#define NN 50000

// ---- weight region (float offsets). O_W2 / O_WN2 hold TRANSPOSED weights.
#define O_W1   0          // We1  [129*64] row-major
#define O_B1   8256
#define O_W2   8320       // We2^T [64*64]
#define O_B2   12416
#define O_WC1  12480      // Wc1  [64*64] row-major
#define O_BC1  16576
#define O_WC2  16640
#define O_BC2  16704
#define O_WN1  16768      // Wn1  [128*64] row-major
#define O_BN1  24960
#define O_WN2  25024      // Wn2^T [64*64]
#define O_BN2  29120
#define O_FLAG 29184      // int: 1 = tensors bf16, 0 = f32

// ---- per-node layer-1 precompute (fp32, R7-proven):
// Y[n][0:64]=h[n]@We1[0:64], Y[n][64:128]=h[n]@We1[64:128]
#define O_Y    29248                    // float [NN*128]
#define Y_END  (O_Y + NN*128)           // 6,429,248

// ---- CSR layout (edge data stored BY POSITION in CSR order) ----
#define N_OFF   Y_END                   // int off[NN+1] (padded to 50008)
#define N_CNT   (N_OFF + 50008)         // int count/cursor[NN]
#define N_RC    (N_CNT + NN)            // int2 (row,col)[NE] by position (8B aligned)
#define N_AGGH  (N_RC + 2*NE)           // float [NN*64]
#define N_SUMT  (N_AGGH + NN*64)        // float [NN*3]
#define N_EF16  (N_SUMT + NN*3 + 2)     // bf16 ef by position: NE*32 words (16B aligned)
#define N_TR    (N_EF16 + NE*32)        // float [NE*3] by position
#define N_TOTAL (N_TR + NE*3)           // ~39.5M words ~ 158 MB

// ---- atomic fallback layout ----
#define F_AGGH  Y_END
#define F_SUMT  (F_AGGH + NN*64)
#define F_CNT   (F_SUMT + NN*3)
#define F_TOTAL (F_CNT + NN)

#define OUT_COORD (NN*64)
#define OUT_V     (NN*64 + NN*3)

static __device__ __forceinline__ float bf2f(const __hip_bfloat16 x) { return __bfloat162float(x); }

template<bool B16>
static __device__ __forceinline__ float ldf(const void* p, size_t i) {
    if (B16) return __bfloat162float(((const __hip_bfloat16*)p)[i]);
    else     return ((const float*)p)[i];
}
template<bool B16>
static __device__ __forceinline__ void stf(void* p, size_t i, float v) {
    if (B16) ((__hip_bfloat16*)p)[i] = __float2bfloat16(v);
    else     ((float*)p)[i] = v;
}
template<bool B16>
static __device__ __forceinline__ float4 ld4(const void* p, size_t i4) {
    if (B16) {
        uint2 u = ((const uint2*)p)[i4];
        return make_float4(__uint_as_float(u.x << 16), __uint_as_float(u.x & 0xffff0000u),
                           __uint_as_float(u.y << 16), __uint_as_float(u.y & 0xffff0000u));
    } else {
        return ((const float4*)p)[i4];
    }
}
template<bool B16>
static __device__ __forceinline__ void st4(void* p, size_t i4, float4 v) {
    if (B16) {
        stf<true>(p, 4*i4 + 0, v.x); stf<true>(p, 4*i4 + 1, v.y);
        stf<true>(p, 4*i4 + 2, v.z); stf<true>(p, 4*i4 + 3, v.w);
    } else {
        ((float4*)p)[i4] = v;
    }
}
static __device__ __forceinline__ unsigned short f2bf_bits(float x) {
    __hip_bfloat16 b = __float2bfloat16(x);
    return *reinterpret_cast<unsigned short*>(&b);
}
static __device__ __forceinline__ uint32_t pack_bf2(float lo, float hi) {
    return (uint32_t)f2bf_bits(lo) | ((uint32_t)f2bf_bits(hi) << 16);
}

// ---- dtype sniff (see R2): P(wrong) ~ 0.48^128 ----
__global__ void sniff_kernel(const uint32_t* __restrict__ w, float* __restrict__ ws) {
    int bad = 0;
    for (int i = 0; i < 128; ++i) {
        uint32_t d = w[i];
        float a = __uint_as_float(d << 16);
        float b = __uint_as_float(d & 0xffff0000u);
        if (!(fabsf(a) <= 0.1f)) bad++;
        if (!(fabsf(b) <= 0.1f)) bad++;
    }
    ((int*)ws)[O_FLAG] = (bad == 0) ? 1 : 0;
}

// ---- weights -> fp32 in ws; W2/Wn2 transposed ----
__global__ void prep_kernel(
    const void* We1, const void* be1, const void* We2, const void* be2,
    const void* Wn1, const void* bn1, const void* Wn2, const void* bn2,
    const void* Wc1, const void* bc1, const void* Wc2, const void* bc2,
    float* __restrict__ wf)
{
    const int isb = ((const int*)wf)[O_FLAG];
    int tid = blockIdx.x * blockDim.x + threadIdx.x;
    int stride = gridDim.x * blockDim.x;
#define LD(src, i) (isb ? bf2f(((const __hip_bfloat16*)(src))[i]) : ((const float*)(src))[i])
#define CP(dst, src, n)  for (int i = tid; i < (n); i += stride) wf[(dst) + i] = LD(src, i);
#define CPT(dst, src)    for (int i = tid; i < 4096; i += stride) \
        wf[(dst) + (i & 63) * 64 + (i >> 6)] = LD(src, i);
    CP(O_W1,  We1, 129*64)  CP(O_B1,  be1, 64)
    CPT(O_W2,  We2)         CP(O_B2,  be2, 64)
    CP(O_WC1, Wc1, 64*64)   CP(O_BC1, bc1, 64)
    CP(O_WC2, Wc2, 64)      CP(O_BC2, bc2, 1)
    CP(O_WN1, Wn1, 128*64)  CP(O_BN1, bn1, 64)
    CPT(O_WN2, Wn2)         CP(O_BN2, bn2, 64)
#undef CP
#undef CPT
#undef LD
}

// ---- per-node layer-1 partials (R7-proven, fp32 out) ----
template<bool B16>
static __device__ __forceinline__ void pre_edge_core(
    const void* __restrict__ h, float* __restrict__ ws, int n)
{
    float yr[64], yc[64];
    #pragma unroll
    for (int j = 0; j < 64; ++j) { yr[j] = 0.0f; yc[j] = 0.0f; }
    #pragma unroll 4
    for (int q = 0; q < 16; ++q) {
        float4 a = ld4<B16>(h, (size_t)n * 16 + q);
        #pragma unroll
        for (int u = 0; u < 4; ++u) {
            int k = q * 4 + u;
            float av = (u == 0) ? a.x : (u == 1) ? a.y : (u == 2) ? a.z : a.w;
            const float* w  = ws + O_W1 + k * 64;
            const float* w2 = ws + O_W1 + (64 + k) * 64;
            #pragma unroll
            for (int j = 0; j < 64; ++j) yr[j] = fmaf(av, w[j], yr[j]);
            #pragma unroll
            for (int j = 0; j < 64; ++j) yc[j] = fmaf(av, w2[j], yc[j]);
        }
    }
    float4* yv = (float4*)(ws + O_Y + (size_t)n * 128);
    #pragma unroll
    for (int q = 0; q < 16; ++q) yv[q]      = make_float4(yr[4*q], yr[4*q+1], yr[4*q+2], yr[4*q+3]);
    #pragma unroll
    for (int q = 0; q < 16; ++q) yv[16 + q] = make_float4(yc[4*q], yc[4*q+1], yc[4*q+2], yc[4*q+3]);
}

__global__ __launch_bounds__(256, 2) void pre_edge_kernel(
    const void* __restrict__ h, float* __restrict__ ws)
{
    int n = blockIdx.x * 256 + threadIdx.x;
    if (n >= NN) return;
    if (((const int*)ws)[O_FLAG]) pre_edge_core<true>(h, ws, n);
    else                          pre_edge_core<false>(h, ws, n);
}

// ---- edge MLP core (R7-proven: fp32 Y, interleaved loads, scalar fmaf) ----
template<bool B16>
static __device__ __forceinline__ void edge_mlp(
    const void* __restrict__ coord, const float* __restrict__ wf,
    int row, int col,
    float4 efbuf[16], float& gate, float& cdx, float& cdy, float& cdz)
{
    cdx = ldf<B16>(coord, 3*row + 0) - ldf<B16>(coord, 3*col + 0);
    cdy = ldf<B16>(coord, 3*row + 1) - ldf<B16>(coord, 3*col + 1);
    cdz = ldf<B16>(coord, 3*row + 2) - ldf<B16>(coord, 3*col + 2);
    float radial = cdx*cdx + cdy*cdy + cdz*cdz;

    const float4* yrv = (const float4*)(wf + O_Y + (size_t)row * 128);
    const float4* ycv = (const float4*)(wf + O_Y + (size_t)col * 128 + 64);

    float acc[64];
    #pragma unroll
    for (int q = 0; q < 16; ++q) {
        float4 a = yrv[q];
        float4 b = ycv[q];
        const float* wr = wf + O_W1 + 128 * 64 + q * 4;
        acc[4*q+0] = fmaxf(fmaf(radial, wr[0], wf[O_B1 + 4*q+0] + a.x + b.x), 0.0f);
        acc[4*q+1] = fmaxf(fmaf(radial, wr[1], wf[O_B1 + 4*q+1] + a.y + b.y), 0.0f);
        acc[4*q+2] = fmaxf(fmaf(radial, wr[2], wf[O_B1 + 4*q+2] + a.z + b.z), 0.0f);
        acc[4*q+3] = fmaxf(fmaf(radial, wr[3], wf[O_B1 + 4*q+3] + a.w + b.w), 0.0f);
    }

    // phase B: ef[j] = relu(acc . We2^T_j + b2_j)
    #pragma unroll
    for (int j0 = 0; j0 < 16; ++j0) {
        float c[4];
        #pragma unroll
        for (int u = 0; u < 4; ++u) {
            int j = j0 * 4 + u;
            float t = wf[O_B2 + j];
            const float* w2t = wf + O_W2 + j * 64;
            #pragma unroll
            for (int k = 0; k < 64; ++k) t = fmaf(acc[k], w2t[k], t);
            c[u] = fmaxf(t, 0.0f);
        }
        efbuf[j0] = make_float4(c[0], c[1], c[2], c[3]);
    }

    // phase C: hid = bc1 + ef . Wc1
    float hid[64];
    #pragma unroll
    for (int j = 0; j < 64; ++j) hid[j] = wf[O_BC1 + j];
    #pragma unroll
    for (int j0 = 0; j0 < 16; ++j0) {
        float4 ef4 = efbuf[j0];
        const float* w0 = wf + O_WC1 + (j0 * 4 + 0) * 64;
        const float* w1 = wf + O_WC1 + (j0 * 4 + 1) * 64;
        const float* w2 = wf + O_WC1 + (j0 * 4 + 2) * 64;
        const float* w3 = wf + O_WC1 + (j0 * 4 + 3) * 64;
        #pragma unroll
        for (int jj = 0; jj < 64; ++jj) hid[jj] = fmaf(ef4.x, w0[jj], hid[jj]);
        #pragma unroll
        for (int jj = 0; jj < 64; ++jj) hid[jj] = fmaf(ef4.y, w1[jj], hid[jj]);
        #pragma unroll
        for (int jj = 0; jj < 64; ++jj) hid[jj] = fmaf(ef4.z, w2[jj], hid[jj]);
        #pragma unroll
        for (int jj = 0; jj < 64; ++jj) hid[jj] = fmaf(ef4.w, w3[jj], hid[jj]);
    }

    float g0 = wf[O_BC2], g1 = 0.0f, g2 = 0.0f, g3 = 0.0f;
    #pragma unroll
    for (int j = 0; j < 64; j += 4) {
        g0 = fmaf(fmaxf(hid[j + 0], 0.0f), wf[O_WC2 + j + 0], g0);
        g1 = fmaf(fmaxf(hid[j + 1], 0.0f), wf[O_WC2 + j + 1], g1);
        g2 = fmaf(fmaxf(hid[j + 2], 0.0f), wf[O_WC2 + j + 2], g2);
        g3 = fmaf(fmaxf(hid[j + 3], 0.0f), wf[O_WC2 + j + 3], g3);
    }
    gate = (g0 + g1) + (g2 + g3);
}

// ============ CSR path ============
// count: histogram of destination rows
__global__ __launch_bounds__(256) void count_kernel(
    const int* __restrict__ ei, float* __restrict__ ws)
{
    int e = blockIdx.x * 256 + threadIdx.x;
    if (e >= NE) return;
    atomicAdd((int*)ws + N_CNT + ei[e], 1);
}

// shfl-based single-block exclusive scan: counts (N_CNT) -> N_OFF; cnt becomes cursor
__global__ __launch_bounds__(1024) void scan_kernel(float* __restrict__ ws) {
    int* cnt = (int*)ws + N_CNT;
    int* off = (int*)ws + N_OFF;
    __shared__ int wsum[16];
    __shared__ int carry_s;
    int tid = threadIdx.x, lane = tid & 63, wid = tid >> 6;
    if (tid == 0) carry_s = 0;
    __syncthreads();
    for (int base = 0; base < NN; base += 1024) {
        int i = base + tid;
        int orig = (i < NN) ? cnt[i] : 0;
        int v = orig;
        #pragma unroll
        for (int s = 1; s < 64; s <<= 1) { int t = __shfl_up(v, s, 64); if (lane >= s) v += t; }
        if (lane == 63) wsum[wid] = v;
        __syncthreads();
        if (wid == 0) {
            int w = (lane < 16) ? wsum[lane] : 0;
            #pragma unroll
            for (int s = 1; s < 16; s <<= 1) { int t = __shfl_up(w, s, 64); if (lane >= s) w += t; }
            if (lane < 16) wsum[lane] = w;
        }
        __syncthreads();
        int waveback = (wid > 0) ? wsum[wid - 1] : 0;
        int excl = carry_s + waveback + v - orig;
        if (i < NN) { off[i] = excl; cnt[i] = excl; }
        __syncthreads();
        if (tid == 0) carry_s += wsum[15];
        __syncthreads();
    }
    if (threadIdx.x == 0) off[NN] = carry_s;
}

// scatter: place (row,col) at CSR position
__global__ __launch_bounds__(256) void scatter_kernel(
    const int* __restrict__ ei, float* __restrict__ ws)
{
    int e = blockIdx.x * 256 + threadIdx.x;
    if (e >= NE) return;
    int row = ei[e];
    int col = ei[NE + e];
    int pos = atomicAdd((int*)ws + N_CNT + row, 1);
    ((int2*)((int*)ws + N_RC))[pos] = make_int2(row, col);
}

// edge MLP in CSR position order: row-side loads hit L1 (consecutive threads
// share row); ef/tr written by position -> agg becomes a sequential stream.
template<bool B16>
static __device__ __forceinline__ void edge_csr_core(
    const void* __restrict__ coord, float* __restrict__ ws, int i)
{
    int2 rc = ((const int2*)((const int*)ws + N_RC))[i];
    float gate, cdx, cdy, cdz;
    float4 efbuf[16];
    edge_mlp<B16>(coord, ws, rc.x, rc.y, efbuf, gate, cdx, cdy, cdz);

    // batched stores (R5 lesson)
    uint4* efv = (uint4*)(ws + N_EF16) + (size_t)i * 8;
    #pragma unroll
    for (int q = 0; q < 8; ++q) {
        float4 a = efbuf[2*q], b = efbuf[2*q + 1];
        efv[q] = make_uint4(pack_bf2(a.x, a.y), pack_bf2(a.z, a.w),
                            pack_bf2(b.x, b.y), pack_bf2(b.z, b.w));
    }
    ws[N_TR + 3*i + 0] = fminf(fmaxf(cdx * gate, -100.0f), 100.0f);
    ws[N_TR + 3*i + 1] = fminf(fmaxf(cdy * gate, -100.0f), 100.0f);
    ws[N_TR + 3*i + 2] = fminf(fmaxf(cdz * gate, -100.0f), 100.0f);
}

__global__ __launch_bounds__(256, 2) void edge_csr_kernel(
    const void* __restrict__ coord, float* __restrict__ ws)
{
    int i = blockIdx.x * 256 + threadIdx.x;
    if (i >= NE) return;
    if (((const int*)ws)[O_FLAG]) edge_csr_core<true>(coord, ws, i);
    else                          edge_csr_core<false>(coord, ws, i);
}

// one wave per node: SEQUENTIAL stream over the node's contiguous positions
__global__ __launch_bounds__(256) void agg_kernel(float* __restrict__ ws) {
    int node = (blockIdx.x * 256 + threadIdx.x) >> 6;
    int lane = threadIdx.x & 63;
    if (node >= NN) return;
    const int* off = (const int*)ws + N_OFF;
    const unsigned short* ef16 = (const unsigned short*)(ws + N_EF16);
    const float* tr = ws + N_TR;
    int s = off[node], t = off[node + 1];
    float sum = 0.0f, ts = 0.0f;
    int i = s;
    for (; i + 4 <= t; i += 4) {
        unsigned short u0 = ef16[(size_t)(i+0) * 64 + lane];
        unsigned short u1 = ef16[(size_t)(i+1) * 64 + lane];
        unsigned short u2 = ef16[(size_t)(i+2) * 64 + lane];
        unsigned short u3 = ef16[(size_t)(i+3) * 64 + lane];
        float t0 = 0.0f, t1 = 0.0f, t2v = 0.0f, t3 = 0.0f;
        if (lane < 3) {
            t0 = tr[3*(i+0) + lane]; t1 = tr[3*(i+1) + lane];
            t2v = tr[3*(i+2) + lane]; t3 = tr[3*(i+3) + lane];
        }
        sum += __uint_as_float((uint32_t)u0 << 16) + __uint_as_float((uint32_t)u1 << 16)
             + __uint_as_float((uint32_t)u2 << 16) + __uint_as_float((uint32_t)u3 << 16);
        ts += (t0 + t1) + (t2v + t3);
    }
    for (; i < t; ++i) {
        unsigned short u = ef16[(size_t)i * 64 + lane];
        sum += __uint_as_float((uint32_t)u << 16);
        if (lane < 3) ts += tr[3*i + lane];
    }
    ws[N_AGGH + (size_t)node * 64 + lane] = sum;
    if (lane < 3) ws[N_SUMT + 3*node + lane] = ts;
}

// ---- node core (R7-proven, batched stores) ----
template<bool B16>
static __device__ __forceinline__ void node_core(
    const void* __restrict__ h, const void* __restrict__ coord,
    const void* __restrict__ vel, const float* __restrict__ ws,
    const float* __restrict__ agg, const float* __restrict__ sumt, float cntf,
    void* __restrict__ out, int n)
{
    float inv = (cntf > 0.0f) ? (1.0f / fmaxf(cntf, 1.0f)) : 0.0f;
    #pragma unroll
    for (int i = 0; i < 3; ++i) {
        float aggc = sumt[3*n + i] * inv;
        float v = ldf<B16>(vel, 3*n + i) + aggc * 0.125f;
        float cn = ldf<B16>(coord, 3*n + i) + v * 0.125f;
        stf<B16>(out, OUT_COORD + 3*n + i, cn);
        stf<B16>(out, OUT_V + 3*n + i, v);
    }

    float acc[64];
    #pragma unroll
    for (int j = 0; j < 64; ++j) acc[j] = ws[O_BN1 + j];

    #pragma unroll 4
    for (int q = 0; q < 16; ++q) {
        float4 a = ld4<B16>(h, (size_t)n * 16 + q);
        const float* w = ws + O_WN1 + (q * 4) * 64;
        #pragma unroll
        for (int j = 0; j < 64; ++j) acc[j] = fmaf(a.x, w[j], acc[j]);
        #pragma unroll
        for (int j = 0; j < 64; ++j) acc[j] = fmaf(a.y, w[64 + j], acc[j]);
        #pragma unroll
        for (int j = 0; j < 64; ++j) acc[j] = fmaf(a.z, w[128 + j], acc[j]);
        #pragma unroll
        for (int j = 0; j < 64; ++j) acc[j] = fmaf(a.w, w[192 + j], acc[j]);
    }
    const float4* agv = (const float4*)(agg + (size_t)n * 64);
    #pragma unroll 4
    for (int q = 0; q < 16; ++q) {
        float4 a = agv[q];
        const float* w = ws + O_WN1 + (64 + q * 4) * 64;
        #pragma unroll
        for (int j = 0; j < 64; ++j) acc[j] = fmaf(a.x, w[j], acc[j]);
        #pragma unroll
        for (int j = 0; j < 64; ++j) acc[j] = fmaf(a.y, w[64 + j], acc[j]);
        #pragma unroll
        for (int j = 0; j < 64; ++j) acc[j] = fmaf(a.z, w[128 + j], acc[j]);
        #pragma unroll
        for (int j = 0; j < 64; ++j) acc[j] = fmaf(a.w, w[192 + j], acc[j]);
    }
    #pragma unroll
    for (int j = 0; j < 64; ++j) acc[j] = fmaxf(acc[j], 0.0f);

    float4 ob[16];
    #pragma unroll
    for (int j0 = 0; j0 < 16; ++j0) {
        float4 hres = ld4<B16>(h, (size_t)n * 16 + j0);
        float c[4];
        #pragma unroll
        for (int u = 0; u < 4; ++u) {
            int j = j0 * 4 + u;
            float t = ws[O_BN2 + j];
            const float* w = ws + O_WN2 + j * 64;
            #pragma unroll
            for (int k = 0; k < 64; ++k) t = fmaf(acc[k], w[k], t);
            c[u] = t;
        }
        ob[j0] = make_float4(hres.x + c[0], hres.y + c[1], hres.z + c[2], hres.w + c[3]);
    }
    #pragma unroll
    for (int j0 = 0; j0 < 16; ++j0) st4<B16>(out, (size_t)n * 16 + j0, ob[j0]);
}

__global__ __launch_bounds__(256, 2) void node_kernel_csr(
    const void* __restrict__ h, const void* __restrict__ coord,
    const void* __restrict__ vel, const float* __restrict__ ws,
    void* __restrict__ out)
{
    int n = blockIdx.x * 256 + threadIdx.x;
    if (n >= NN) return;
    const int* off = (const int*)ws + N_OFF;
    float cntf = (float)(off[n + 1] - off[n]);
    if (((const int*)ws)[O_FLAG])
        node_core<true>(h, coord, vel, ws, ws + N_AGGH, ws + N_SUMT, cntf, out, n);
    else
        node_core<false>(h, coord, vel, ws, ws + N_AGGH, ws + N_SUMT, cntf, out, n);
}

// ============ atomic fallback (small ws) ============
template<bool B16>
static __device__ __forceinline__ void edge_atomic_core(
    const void* __restrict__ coord, const int* __restrict__ ei,
    float* __restrict__ ws, int e)
{
    int row = ei[e];
    int col = ei[NE + e];
    float gate, cdx, cdy, cdz;
    float4 efbuf[16];
    edge_mlp<B16>(coord, ws, row, col, efbuf, gate, cdx, cdy, cdz);

    float* ah = ws + F_AGGH + (size_t)row * 64;
    #pragma unroll
    for (int q = 0; q < 16; ++q) {
        unsafeAtomicAdd(&ah[4*q + 0], efbuf[q].x);
        unsafeAtomicAdd(&ah[4*q + 1], efbuf[q].y);
        unsafeAtomicAdd(&ah[4*q + 2], efbuf[q].z);
        unsafeAtomicAdd(&ah[4*q + 3], efbuf[q].w);
    }
    unsafeAtomicAdd(&ws[F_SUMT + 3*row + 0], fminf(fmaxf(cdx * gate, -100.0f), 100.0f));
    unsafeAtomicAdd(&ws[F_SUMT + 3*row + 1], fminf(fmaxf(cdy * gate, -100.0f), 100.0f));
    unsafeAtomicAdd(&ws[F_SUMT + 3*row + 2], fminf(fmaxf(cdz * gate, -100.0f), 100.0f));
    unsafeAtomicAdd(&ws[F_CNT + row], 1.0f);
}

__global__ __launch_bounds__(256, 2) void edge_atomic_kernel(
    const void* __restrict__ coord, const int* __restrict__ ei,
    float* __restrict__ ws)
{
    int e = blockIdx.x * 256 + threadIdx.x;
    if (e >= NE) return;
    if (((const int*)ws)[O_FLAG]) edge_atomic_core<true>(coord, ei, ws, e);
    else                          edge_atomic_core<false>(coord, ei, ws, e);
}

__global__ __launch_bounds__(256, 2) void node_kernel_atomic(
    const void* __restrict__ h, const void* __restrict__ coord,
    const void* __restrict__ vel, const float* __restrict__ ws,
    void* __restrict__ out)
{
    int n = blockIdx.x * 256 + threadIdx.x;
    if (n >= NN) return;
    float cntf = ws[F_CNT + n];
    if (((const int*)ws)[O_FLAG])
        node_core<true>(h, coord, vel, ws, ws + F_AGGH, ws + F_SUMT, cntf, out, n);
    else
        node_core<false>(h, coord, vel, ws, ws + F_AGGH, ws + F_SUMT, cntf, out, n);
}

extern "C" void kernel_launch(void* const* d_in, const int* in_sizes, int n_in,
                              void* d_out, int out_size, void* d_ws, size_t ws_size,
                              hipStream_t stream) {
    const void* h     = d_in[0];
    const void* coord = d_in[1];
    const void* vel   = d_in[2];
    const int* eidx = (const int*)d_in[4];
    float* ws = (float*)d_ws;

    sniff_kernel<<<1, 1, 0, stream>>>((const uint32_t*)d_in[5], ws);
    prep_kernel<<<64, 256, 0, stream>>>(d_in[5], d_in[6], d_in[7], d_in[8],
                                        d_in[9], d_in[10], d_in[11], d_in[12],
                                        d_in[13], d_in[14], d_in[15], d_in[16], ws);
    pre_edge_kernel<<<(NN + 255) / 256, 256, 0, stream>>>(h, ws);

    const bool big = ws_size >= (size_t)N_TOTAL * sizeof(float);
    if (big) {
        hipMemsetAsync((char*)d_ws + (size_t)N_CNT * 4, 0, (size_t)NN * 4, stream);
        count_kernel<<<(NE + 255) / 256, 256, 0, stream>>>(eidx, ws);
        scan_kernel<<<1, 1024, 0, stream>>>(ws);
        scatter_kernel<<<(NE + 255) / 256, 256, 0, stream>>>(eidx, ws);
        edge_csr_kernel<<<(NE + 255) / 256, 256, 0, stream>>>(coord, ws);
        agg_kernel<<<(NN * 64 + 255) / 256, 256, 0, stream>>>(ws);
        node_kernel_csr<<<(NN + 255) / 256, 256, 0, stream>>>(h, coord, vel, ws, d_out);
    } else {
        hipMemsetAsync((char*)d_ws + (size_t)F_AGGH * 4, 0,
                       (size_t)(F_TOTAL - F_AGGH) * 4, stream);
        edge_atomic_kernel<<<(NE + 255) / 256, 256, 0, stream>>>(coord, eidx, ws);
        node_kernel_atomic<<<(NN + 255) / 256, 256, 0, stream>>>(h, coord, vel, ws, d_out);
    }
}